// Round 1
// baseline (3614.625 us; speedup 1.0000x reference)
//
#include <hip/hip_runtime.h>
#include <hip/hip_bf16.h>
#include <math.h>

// Problem constants
constexpr int cB   = 2;
constexpr int cS   = 2048;
constexpr int cD   = 1024;
constexpr int cQH  = 16;
constexpr int cKVH = 4;
constexpr int cDH  = 64;
constexpr int cTOPK = 128;
constexpr int cM   = cB * cS;          // 4096 rows for all GEMMs

// ---------------------------------------------------------------------------
// GEMM: C[m][n] = sum_k A[m*K+k] * W[n*K+k]   (i.e. A @ W^T), fp32 tiled.
// M,N multiples of 64; K multiple of 16.
// ---------------------------------------------------------------------------
__global__ __launch_bounds__(256) void gemm_xwT(const float* __restrict__ A,
                                                const float* __restrict__ W,
                                                float* __restrict__ C,
                                                int M, int N, int K) {
    __shared__ float As[16][64 + 1];
    __shared__ float Ws[16][64 + 1];
    const int tid = threadIdx.x;
    const int tx = tid & 15;        // 0..15 col group
    const int ty = tid >> 4;        // 0..15 row group
    const int m0 = blockIdx.y * 64;
    const int n0 = blockIdx.x * 64;

    float acc[4][4] = {};

    const int lrow = tid >> 2;          // 0..63
    const int lkk  = (tid & 3) * 4;     // 0,4,8,12

    for (int k0 = 0; k0 < K; k0 += 16) {
        const float4 a4 = *(const float4*)(A + (size_t)(m0 + lrow) * K + k0 + lkk);
        As[lkk + 0][lrow] = a4.x;
        As[lkk + 1][lrow] = a4.y;
        As[lkk + 2][lrow] = a4.z;
        As[lkk + 3][lrow] = a4.w;
        const float4 w4 = *(const float4*)(W + (size_t)(n0 + lrow) * K + k0 + lkk);
        Ws[lkk + 0][lrow] = w4.x;
        Ws[lkk + 1][lrow] = w4.y;
        Ws[lkk + 2][lrow] = w4.z;
        Ws[lkk + 3][lrow] = w4.w;
        __syncthreads();

        #pragma unroll
        for (int kk = 0; kk < 16; ++kk) {
            float a[4], w[4];
            #pragma unroll
            for (int x = 0; x < 4; ++x) a[x] = As[kk][ty * 4 + x];
            #pragma unroll
            for (int x = 0; x < 4; ++x) w[x] = Ws[kk][tx * 4 + x];
            #pragma unroll
            for (int y = 0; y < 4; ++y)
                #pragma unroll
                for (int x = 0; x < 4; ++x)
                    acc[y][x] += a[y] * w[x];
        }
        __syncthreads();
    }

    #pragma unroll
    for (int y = 0; y < 4; ++y) {
        const int m = m0 + ty * 4 + y;
        float4 r = make_float4(acc[y][0], acc[y][1], acc[y][2], acc[y][3]);
        *(float4*)(C + (size_t)m * N + n0 + tx * 4) = r;
    }
}

// ---------------------------------------------------------------------------
// RoPE in place. buf layout: (B*S, H, DH) row-major. Half-split rotation.
// One thread per (row, h, d<32) pair.
// ---------------------------------------------------------------------------
__global__ void rope_kernel(float* __restrict__ buf, int H, int total) {
    int idx = blockIdx.x * blockDim.x + threadIdx.x;
    if (idx >= total) return;
    const int d   = idx & 31;
    const int h   = (idx >> 5) % H;
    const int row = idx / (32 * H);
    const int s   = row % cS;
    const float inv_freq = powf(10000.0f, -(float)d / 32.0f);
    const float ang = (float)s * inv_freq;
    const float c  = cosf(ang);
    const float si = sinf(ang);
    float* p = buf + (size_t)row * H * cDH + (size_t)h * cDH;
    const float x1 = p[d];
    const float x2 = p[d + 32];
    p[d]      = x1 * c - x2 * si;
    p[d + 32] = x2 * c + x1 * si;
}

// ---------------------------------------------------------------------------
// Order-preserving float <-> uint bit maps (no NaNs in this problem).
// ---------------------------------------------------------------------------
__device__ inline unsigned fmap(float f) {
    unsigned u = __float_as_uint(f);
    return (u & 0x80000000u) ? ~u : (u | 0x80000000u);
}
__device__ inline float funmap(unsigned u) {
    unsigned v = (u & 0x80000000u) ? (u & 0x7FFFFFFFu) : ~u;
    return __uint_as_float(v);
}

// ---------------------------------------------------------------------------
// Attention with exact top-k threshold, one workgroup per (b, h, i) row.
// q,k,v layouts: q (B,S,QH,DH), k/v (B,S,KVH,DH). out: (B,S,QH,DH).
// ---------------------------------------------------------------------------
__global__ __launch_bounds__(256) void attn_topk_kernel(
        const float* __restrict__ q, const float* __restrict__ k,
        const float* __restrict__ v, float* __restrict__ out) {
    __shared__ float sc[cS];        // scores
    __shared__ float wl[cS];        // kept weights (exp(s-m))
    __shared__ int   jl[cS];        // kept indices
    __shared__ int   hist[256];
    __shared__ float qrow[cDH];
    __shared__ float red[256];
    __shared__ float oacc[4][cDH];
    __shared__ int   s_rem, s_cnt;
    __shared__ unsigned s_prefix;

    const int tid = threadIdx.x;
    const int bid = blockIdx.x;
    const int i = bid % cS;
    const int h = (bid / cS) % cQH;
    const int b = bid / (cS * cQH);
    const int kvh = h / (cQH / cKVH);   // jnp.repeat(k, rep, axis=1) -> h/rep

    if (tid < cDH)
        qrow[tid] = q[((size_t)(b * cS + i) * cQH + h) * cDH + tid];
    if (tid == 0) { s_rem = cTOPK; s_cnt = 0; s_prefix = 0u; }
    __syncthreads();

    // --- scores: s_j = q . k_j / sqrt(DH), causal mask as -inf -------------
    for (int j = tid; j < cS; j += 256) {
        float val = -INFINITY;
        if (j <= i) {
            const float* kp = k + ((size_t)(b * cS + j) * cKVH + kvh) * cDH;
            float acc = 0.f;
            #pragma unroll
            for (int d = 0; d < cDH; d += 4) {
                float4 k4 = *(const float4*)(kp + d);
                acc += qrow[d] * k4.x + qrow[d + 1] * k4.y
                     + qrow[d + 2] * k4.z + qrow[d + 3] * k4.w;
            }
            val = acc * 0.125f;   // 1/sqrt(64)
        }
        sc[j] = val;
    }
    __syncthreads();

    // --- exact 128th-largest via MSB-first radix-256 select ----------------
    unsigned pmask = 0u;
    for (int p = 3; p >= 0; --p) {
        hist[tid] = 0;
        __syncthreads();
        const unsigned pref = s_prefix;
        for (int j = tid; j < cS; j += 256) {
            unsigned key = fmap(sc[j]);
            if ((key & pmask) == pref)
                atomicAdd(&hist[(key >> (p * 8)) & 0xFF], 1);
        }
        __syncthreads();
        if (tid == 0) {
            int rem = s_rem, cum = 0, bsel = 0;
            for (int bin = 255; bin >= 0; --bin) {
                const int c = hist[bin];
                if (cum + c >= rem) { bsel = bin; break; }
                cum += c;
            }
            s_rem = rem - cum;
            s_prefix = pref | ((unsigned)bsel << (p * 8));
        }
        __syncthreads();
        pmask |= 0xFFu << (p * 8);
    }
    const float thr = funmap(s_prefix);

    // --- row max -----------------------------------------------------------
    float lmax = -INFINITY;
    for (int j = tid; j < cS; j += 256) lmax = fmaxf(lmax, sc[j]);
    red[tid] = lmax;
    __syncthreads();
    for (int s2 = 128; s2 > 0; s2 >>= 1) {
        if (tid < s2) red[tid] = fmaxf(red[tid], red[tid + s2]);
        __syncthreads();
    }
    const float m = red[0];

    // --- compact kept entries (score >= thr keeps ties, like the ref) ------
    for (int j = tid; j < cS; j += 256) {
        const float s = sc[j];
        if (j <= i && s >= thr) {
            const int pos = atomicAdd(&s_cnt, 1);
            jl[pos] = j;
            wl[pos] = __expf(s - m);
        }
    }
    __syncthreads();
    const int cnt = s_cnt;

    // --- sum of weights ----------------------------------------------------
    float lsum = 0.f;
    for (int idx = tid; idx < cnt; idx += 256) lsum += wl[idx];
    red[tid] = lsum;
    __syncthreads();
    for (int s2 = 128; s2 > 0; s2 >>= 1) {
        if (tid < s2) red[tid] += red[tid + s2];
        __syncthreads();
    }
    const float invZ = 1.0f / red[0];

    // --- out[d] = sum_kept w * v[j][d] / Z ---------------------------------
    const int d = tid & 63;
    const int c = tid >> 6;
    float acc = 0.f;
    for (int idx = c; idx < cnt; idx += 4) {
        const int j = jl[idx];
        acc += wl[idx] * v[((size_t)(b * cS + j) * cKVH + kvh) * cDH + d];
    }
    oacc[c][d] = acc;
    __syncthreads();
    if (tid < cDH) {
        const float r = (oacc[0][tid] + oacc[1][tid] + oacc[2][tid] + oacc[3][tid]) * invZ;
        out[((size_t)(b * cS + i) * cQH + h) * cDH + tid] = r;
    }
}

// ---------------------------------------------------------------------------
// Launch
// ---------------------------------------------------------------------------
extern "C" void kernel_launch(void* const* d_in, const int* in_sizes, int n_in,
                              void* d_out, int out_size, void* d_ws, size_t ws_size,
                              hipStream_t stream) {
    const float* x  = (const float*)d_in[0];
    const float* Wq = (const float*)d_in[1];
    const float* Wk = (const float*)d_in[2];
    const float* Wv = (const float*)d_in[3];
    const float* Wo = (const float*)d_in[4];
    float* out = (float*)d_out;

    float* ws = (float*)d_ws;
    float* qb = ws;                                   // (B,S,QH,DH)  4096*1024
    float* kb = qb + (size_t)cM * cQH * cDH;          // (B,S,KVH,DH) 4096*256
    float* vb = kb + (size_t)cM * cKVH * cDH;         // (B,S,KVH,DH) 4096*256
    float* ab = vb + (size_t)cM * cKVH * cDH;         // (B,S,QH,DH)  4096*1024
    // total ws use: 4096*2560 floats = 40 MB

    dim3 blk(256);

    // QKV projections
    gemm_xwT<<<dim3((cQH * cDH) / 64, cM / 64), blk, 0, stream>>>(x, Wq, qb, cM, cQH * cDH, cD);
    gemm_xwT<<<dim3((cKVH * cDH) / 64, cM / 64), blk, 0, stream>>>(x, Wk, kb, cM, cKVH * cDH, cD);
    gemm_xwT<<<dim3((cKVH * cDH) / 64, cM / 64), blk, 0, stream>>>(x, Wv, vb, cM, cKVH * cDH, cD);

    // RoPE on q and k (in place)
    {
        int totq = cM * cQH * 32;
        int totk = cM * cKVH * 32;
        rope_kernel<<<(totq + 255) / 256, blk, 0, stream>>>(qb, cQH, totq);
        rope_kernel<<<(totk + 255) / 256, blk, 0, stream>>>(kb, cKVH, totk);
    }

    // Attention with exact top-k threshold
    attn_topk_kernel<<<cB * cQH * cS, blk, 0, stream>>>(qb, kb, vb, ab);

    // Output projection
    gemm_xwT<<<dim3(cD / 64, cM / 64), blk, 0, stream>>>(ab, Wo, out, cM, cD, cD);
}

// Round 2
// 1364.414 us; speedup vs baseline: 2.6492x; 2.6492x over previous
//
#include <hip/hip_runtime.h>
#include <hip/hip_bf16.h>
#include <math.h>

// Problem constants
constexpr int cB   = 2;
constexpr int cS   = 2048;
constexpr int cD   = 1024;
constexpr int cQH  = 16;
constexpr int cKVH = 4;
constexpr int cDH  = 64;
constexpr int cTOPK = 128;
constexpr int cM   = cB * cS;          // 4096 rows for all GEMMs
constexpr int cNB  = cS / 64;          // 32 j-blocks of 64
constexpr int cLSZ = 384;              // kept-list capacity (128 + tie slack)

// ---------------------------------------------------------------------------
// GEMM: C[m][n] = sum_k A[m*K+k] * W[n*K+k]   (A @ W^T), fp32 tiled.
// ---------------------------------------------------------------------------
__global__ __launch_bounds__(256) void gemm_xwT(const float* __restrict__ A,
                                                const float* __restrict__ W,
                                                float* __restrict__ C,
                                                int M, int N, int K) {
    __shared__ float As[16][64 + 1];
    __shared__ float Ws[16][64 + 1];
    const int tid = threadIdx.x;
    const int tx = tid & 15;
    const int ty = tid >> 4;
    const int m0 = blockIdx.y * 64;
    const int n0 = blockIdx.x * 64;

    float acc[4][4] = {};
    const int lrow = tid >> 2;
    const int lkk  = (tid & 3) * 4;

    for (int k0 = 0; k0 < K; k0 += 16) {
        const float4 a4 = *(const float4*)(A + (size_t)(m0 + lrow) * K + k0 + lkk);
        As[lkk + 0][lrow] = a4.x;
        As[lkk + 1][lrow] = a4.y;
        As[lkk + 2][lrow] = a4.z;
        As[lkk + 3][lrow] = a4.w;
        const float4 w4 = *(const float4*)(W + (size_t)(n0 + lrow) * K + k0 + lkk);
        Ws[lkk + 0][lrow] = w4.x;
        Ws[lkk + 1][lrow] = w4.y;
        Ws[lkk + 2][lrow] = w4.z;
        Ws[lkk + 3][lrow] = w4.w;
        __syncthreads();

        #pragma unroll
        for (int kk = 0; kk < 16; ++kk) {
            float a[4], w[4];
            #pragma unroll
            for (int x = 0; x < 4; ++x) a[x] = As[kk][ty * 4 + x];
            #pragma unroll
            for (int x = 0; x < 4; ++x) w[x] = Ws[kk][tx * 4 + x];
            #pragma unroll
            for (int y = 0; y < 4; ++y)
                #pragma unroll
                for (int x = 0; x < 4; ++x)
                    acc[y][x] += a[y] * w[x];
        }
        __syncthreads();
    }

    #pragma unroll
    for (int y = 0; y < 4; ++y) {
        const int m = m0 + ty * 4 + y;
        float4 r = make_float4(acc[y][0], acc[y][1], acc[y][2], acc[y][3]);
        *(float4*)(C + (size_t)m * N + n0 + tx * 4) = r;
    }
}

// ---------------------------------------------------------------------------
// RoPE in place. buf layout: (B*S, H, DH) row-major. Half-split rotation.
// ---------------------------------------------------------------------------
__global__ void rope_kernel(float* __restrict__ buf, int H, int total) {
    int idx = blockIdx.x * blockDim.x + threadIdx.x;
    if (idx >= total) return;
    const int d   = idx & 31;
    const int h   = (idx >> 5) % H;
    const int row = idx / (32 * H);
    const int s   = row % cS;
    const float inv_freq = powf(10000.0f, -(float)d / 32.0f);
    const float ang = (float)s * inv_freq;
    const float c  = cosf(ang);
    const float si = sinf(ang);
    float* p = buf + (size_t)row * H * cDH + (size_t)h * cDH;
    const float x1 = p[d];
    const float x2 = p[d + 32];
    p[d]      = x1 * c - x2 * si;
    p[d + 32] = x2 * c + x1 * si;
}

// ---------------------------------------------------------------------------
// Order-preserving float <-> uint bit maps (no NaNs here).
// ---------------------------------------------------------------------------
__device__ inline unsigned fmap(float f) {
    unsigned u = __float_as_uint(f);
    return (u & 0x80000000u) ? ~u : (u | 0x80000000u);
}
__device__ inline float funmap(unsigned u) {
    unsigned v = (u & 0x80000000u) ? (u & 0x7FFFFFFFu) : ~u;
    return __uint_as_float(v);
}

// ---------------------------------------------------------------------------
// Wave-per-row attention with exact top-k threshold. No __syncthreads.
// Block = 256 threads = 4 waves = 4 query rows.
// q (B,S,QH,DH), k/v (B,S,KVH,DH), out (B,S,QH,DH) all fp32.
// ---------------------------------------------------------------------------
__global__ __launch_bounds__(256) void attn_wave_kernel(
        const float* __restrict__ q, const float* __restrict__ k,
        const float* __restrict__ v, float* __restrict__ out) {
    __shared__ unsigned klist[4][cLSZ];   // keys, later overwritten by weights
    __shared__ int      jlist[4][cLSZ];

    const int lane = threadIdx.x & 63;
    const int w    = threadIdx.x >> 6;
    const int gid  = blockIdx.x * 4 + w;

    // wave-uniform row decode (force scalar)
    const int i   = __builtin_amdgcn_readfirstlane(gid % cS);
    const int h   = __builtin_amdgcn_readfirstlane((gid / cS) % cQH);
    const int b   = __builtin_amdgcn_readfirstlane(gid / (cS * cQH));
    const int kvh = h / (cQH / cKVH);
    const int nb  = (i >> 6) + 1;         // causal j-blocks of 64

    const int g  = lane >> 2;             // j-offset within 16-row group
    const int cq = lane & 3;              // 16B chunk id

    // q chunks for this lane: chunk (t*4 + cq), t = 0..3
    const float4* qv = (const float4*)(q + ((size_t)(b * cS + i) * cQH + h) * cDH);
    float4 qreg[4];
    #pragma unroll
    for (int t = 0; t < 4; ++t) qreg[t] = qv[t * 4 + cq];

    const float4* kvec = (const float4*)k;
    const size_t  bS   = (size_t)b * cS;

    // --- scores -> per-lane uint keys (key[jb] is score j = jb*64 + lane) --
    unsigned key[cNB];
    #pragma unroll
    for (int jb = 0; jb < cNB; ++jb) {
        unsigned kreg = 0u;
        if (jb < nb) {
            #pragma unroll
            for (int u = 0; u < 4; ++u) {
                const int j = (jb << 6) + (u << 4) + g;
                const float4* kp = kvec + ((size_t)(bS + j) * cKVH + kvh) * 16;
                float acc = 0.f;
                #pragma unroll
                for (int t = 0; t < 4; ++t) {
                    const float4 k4 = kp[t * 4 + cq];
                    const float4 q4 = qreg[t];
                    acc += q4.x * k4.x + q4.y * k4.y + q4.z * k4.z + q4.w * k4.w;
                }
                acc += __shfl_xor(acc, 1);
                acc += __shfl_xor(acc, 2);
                const float sv = __shfl(acc, (lane & 15) << 2);
                if ((lane >> 4) == u) {
                    const int jm = (jb << 6) + lane;
                    kreg = (jm <= i) ? fmap(sv * 0.125f) : 0u;
                }
            }
        }
        key[jb] = kreg;
    }

    // --- row max (uint max == float max under the order map) ---------------
    unsigned um = 0u;
    #pragma unroll
    for (int jb = 0; jb < cNB; ++jb) um = max(um, key[jb]);
    #pragma unroll
    for (int off = 32; off >= 1; off >>= 1)
        um = max(um, (unsigned)__shfl_xor((int)um, off));
    const float mrow = funmap(um);

    // --- exact 128th-largest key via bisection on uint space ---------------
    unsigned lo = 0u, hi = 0xFFFFFFFFu;
    while (lo < hi) {
        const unsigned d  = hi - lo;
        const unsigned mid = lo + (d >> 1) + (d & 1u);
        int c = 0;
        #pragma unroll
        for (int jb = 0; jb < cNB; ++jb) {
            if (jb >= nb) break;
            c += __popcll(__ballot(key[jb] >= mid));
        }
        if (c >= cTOPK) lo = mid; else hi = mid - 1u;
    }
    const unsigned ustar = lo;   // 0 when fewer than TOPK valid -> keep all

    // --- ballot-prefix compaction of kept (j, key) into LDS ----------------
    const unsigned long long mlt = (1ull << lane) - 1ull;
    int base = 0;
    #pragma unroll
    for (int jb = 0; jb < cNB; ++jb) {
        if (jb >= nb) break;
        const int j = (jb << 6) + lane;
        const bool keep = (j <= i) && (key[jb] >= ustar);
        const unsigned long long mk = __ballot(keep);
        const int pos = base + __popcll(mk & mlt);
        if (keep && pos < cLSZ) { klist[w][pos] = key[jb]; jlist[w][pos] = j; }
        base += __popcll(mk);
    }
    const int cnt = min(base, cLSZ);

    // --- weights + Z (overwrite keys with weights in place) ----------------
    float zp = 0.f;
    for (int t = lane; t < cnt; t += 64) {
        const float s  = funmap(klist[w][t]);
        const float wt = __expf(s - mrow);
        ((float*)klist[w])[t] = wt;
        zp += wt;
    }
    #pragma unroll
    for (int off = 32; off >= 1; off >>= 1) zp += __shfl_xor(zp, off);
    const float invZ = 1.0f / zp;

    // --- PV: lane = d, broadcast (w, j) from LDS, coalesced v rows ---------
    float acc = 0.f;
    #pragma unroll 4
    for (int t = 0; t < cnt; ++t) {
        const float wt = ((float*)klist[w])[t];
        const int   j  = jlist[w][t];
        acc += wt * v[((size_t)(bS + j) * cKVH + kvh) * cDH + lane];
    }
    out[((size_t)(bS + i) * cQH + h) * cDH + lane] = acc * invZ;
}

// ---------------------------------------------------------------------------
// Launch
// ---------------------------------------------------------------------------
extern "C" void kernel_launch(void* const* d_in, const int* in_sizes, int n_in,
                              void* d_out, int out_size, void* d_ws, size_t ws_size,
                              hipStream_t stream) {
    const float* x  = (const float*)d_in[0];
    const float* Wq = (const float*)d_in[1];
    const float* Wk = (const float*)d_in[2];
    const float* Wv = (const float*)d_in[3];
    const float* Wo = (const float*)d_in[4];
    float* out = (float*)d_out;

    float* ws = (float*)d_ws;
    float* qb = ws;                                   // (B,S,QH,DH)
    float* kb = qb + (size_t)cM * cQH * cDH;          // (B,S,KVH,DH)
    float* vb = kb + (size_t)cM * cKVH * cDH;         // (B,S,KVH,DH)
    float* ab = vb + (size_t)cM * cKVH * cDH;         // (B,S,QH,DH)

    dim3 blk(256);

    gemm_xwT<<<dim3((cQH * cDH) / 64, cM / 64), blk, 0, stream>>>(x, Wq, qb, cM, cQH * cDH, cD);
    gemm_xwT<<<dim3((cKVH * cDH) / 64, cM / 64), blk, 0, stream>>>(x, Wk, kb, cM, cKVH * cDH, cD);
    gemm_xwT<<<dim3((cKVH * cDH) / 64, cM / 64), blk, 0, stream>>>(x, Wv, vb, cM, cKVH * cDH, cD);

    {
        int totq = cM * cQH * 32;
        int totk = cM * cKVH * 32;
        rope_kernel<<<(totq + 255) / 256, blk, 0, stream>>>(qb, cQH, totq);
        rope_kernel<<<(totk + 255) / 256, blk, 0, stream>>>(kb, cKVH, totk);
    }

    attn_wave_kernel<<<(cB * cQH * cS) / 4, blk, 0, stream>>>(qb, kb, vb, ab);

    gemm_xwT<<<dim3(cD / 64, cM / 64), blk, 0, stream>>>(ab, Wo, out, cM, cD, cD);
}